// Round 12
// baseline (396.467 us; speedup 1.0000x reference)
//
#include <hip/hip_runtime.h>
#include <hip/hip_bf16.h>

#define BB 2
#define SS 2048
#define DDIM 1024
#define HH 16
#define DHH 64
#define DFF_ 4096
#define BS 4096   // B*S
#define NQKV 3072 // Q|K|V concatenated feature dim

typedef unsigned short u16;
using short8  = __attribute__((ext_vector_type(8))) short;
using floatx4 = __attribute__((ext_vector_type(4))) float;
using ushort4_t = __attribute__((ext_vector_type(4))) unsigned short;

#define VMW(n) asm volatile("s_waitcnt vmcnt(" #n ")" ::: "memory")

__device__ __forceinline__ u16 f2b(float f){
  union { unsigned int u; float f; } v; v.f = f;
  unsigned int u = v.u;
  u += 0x7FFFu + ((u >> 16) & 1u);   // RNE
  return (u16)(u >> 16);
}

__device__ __forceinline__ void gl2lds16(const u16* g, u16* l){
  __builtin_amdgcn_global_load_lds((const __attribute__((address_space(1))) void*)g,
                                   (__attribute__((address_space(3))) void*)l, 16, 0, 0);
}

// ---------------- LayerNorm row (device): y_bf16 = (x-mu)*rsqrt(var+eps)*gamma + beta ----------------
__device__ __forceinline__ void ln_row(const float* __restrict__ x,
                                       const float* __restrict__ gamma,
                                       const float* __restrict__ beta,
                                       u16* __restrict__ y, int row, float* smem){
  const float4* xr = (const float4*)(x + (size_t)row * DDIM);
  int tid = threadIdx.x;
  float4 v = xr[tid];
  float s  = v.x + v.y + v.z + v.w;
  float ss = v.x*v.x + v.y*v.y + v.z*v.z + v.w*v.w;
  for (int o = 1; o < 64; o <<= 1){ s += __shfl_xor(s, o, 64); ss += __shfl_xor(ss, o, 64); }
  int wid = tid >> 6;
  if ((tid & 63) == 0){ smem[wid] = s; smem[wid + 4] = ss; }
  __syncthreads();
  s  = smem[0] + smem[1] + smem[2] + smem[3];
  ss = smem[4] + smem[5] + smem[6] + smem[7];
  float mu  = s / (float)DDIM;
  float var = ss / (float)DDIM - mu * mu;
  float rs  = rsqrtf(var + 1e-5f);
  const float4* gp = (const float4*)gamma;
  const float4* bp = (const float4*)beta;
  float4 g = gp[tid], b = bp[tid];
  u16* yr = y + (size_t)row * DDIM + tid*4;
  yr[0] = f2b((v.x - mu) * rs * g.x + b.x);
  yr[1] = f2b((v.y - mu) * rs * g.y + b.y);
  yr[2] = f2b((v.z - mu) * rs * g.z + b.z);
  yr[3] = f2b((v.w - mu) * rs * g.w + b.w);
}

// ---------------- transpose+cast tile helper: out_bf16[c][r] = in_f32[r][c] ----------------
__device__ __forceinline__ void tcast(const float* __restrict__ in, u16* __restrict__ out,
                                      int R, int C, int tile, float (*sh)[33]){
  int nr = R >> 5;
  int tr = tile % nr, tc = tile / nr;
  int r0 = tr * 32, c0 = tc * 32;
  int tx = threadIdx.x & 31, ty = threadIdx.x >> 5;   // ty 0..7
  for (int i = ty; i < 32; i += 8)
    sh[i][tx] = in[(size_t)(r0 + i) * C + c0 + tx];
  __syncthreads();
  for (int i = ty; i < 32; i += 8)
    out[(size_t)(c0 + i) * R + r0 + tx] = f2b(sh[tx][i]);
}

// ---------------- fused: LN1 + Wq/Wk/Wv/W0/W1 transposes + bias concat, 1 launch ----------------
__global__ __launch_bounds__(256) void prep_ln1_k(
    const float* __restrict__ X, const float* __restrict__ g1, const float* __restrict__ be1,
    u16* __restrict__ Xn,
    const float* __restrict__ Wq, const float* __restrict__ Wk, const float* __restrict__ Wv,
    const float* __restrict__ W0, const float* __restrict__ W1,
    const float* __restrict__ bq, const float* __restrict__ bk, const float* __restrict__ bv,
    u16* __restrict__ wqkvT, u16* __restrict__ w0T, u16* __restrict__ w1T,
    float* __restrict__ biasQKV)
{
  __shared__ float sh[32][33];
  __shared__ float smem8[8];
  int id = blockIdx.x;
  if (id < 4096){
    ln_row(X, g1, be1, Xn, id, smem8);
  } else if (id < 7168){
    int lid2 = id - 4096;
    int which = lid2 >> 10, lid = lid2 & 1023;
    const float* src = which == 0 ? Wq : (which == 1 ? Wk : Wv);
    u16* dst = wqkvT + (size_t)which * 1048576;
    int bat = lid >> 6, t = lid & 63;              // 64 tiles per [1024][64] head
    tcast(src + (size_t)bat * 65536, dst + (size_t)bat * 65536, 1024, 64, t, sh);
  } else if (id < 8192){
    tcast(W0, w0T, 1024, 1024, id - 7168, sh);
  } else if (id < 12288){
    tcast(W1, w1T, 1024, 4096, id - 8192, sh);
  } else {
    int idx = (id - 12288) * 256 + threadIdx.x;
    if (idx < 3072){
      float v = idx < 1024 ? bq[idx] : (idx < 2048 ? bk[idx - 1024] : bv[idx - 2048]);
      biasQKV[idx] = v;
    }
  }
}

// ---------------- fused: LN2 + W2 transpose, 1 launch ----------------
__global__ __launch_bounds__(256) void w2t_ln2_k(
    const float* __restrict__ X1, const float* __restrict__ g2, const float* __restrict__ be2,
    u16* __restrict__ Xn2, const float* __restrict__ W2, u16* __restrict__ w2T)
{
  __shared__ float sh[32][33];
  __shared__ float smem8[8];
  int id = blockIdx.x;
  if (id < 4096){
    ln_row(X1, g2, be2, Xn2, id, smem8);
  } else {
    int tile = id - 4096;
    int tr = tile / 32, tc = tile % 32;   // R=4096, C=1024
    int r0 = tr * 32, c0 = tc * 32;
    int tx = threadIdx.x & 31, ty = threadIdx.x >> 5;
    for (int i = ty; i < 32; i += 8)
      sh[i][tx] = W2[(size_t)(r0 + i) * 1024 + c0 + tx];
    __syncthreads();
    for (int i = ty; i < 32; i += 8)
      w2T[(size_t)(c0 + i) * 4096 + r0 + tx] = f2b(sh[tx][i]);
  }
}

// ---------------- V-transpose: VT[bh][dh][s] = QKV[b*S+s][2048 + h*64 + dh] ----------------
__global__ __launch_bounds__(256) void vt_k(const u16* __restrict__ QKV, u16* __restrict__ VT){
  __shared__ u16 t[32][33];
  int bh = blockIdx.z; int b = bh >> 4, h = bh & 15;
  int s0 = blockIdx.x * 32, d0 = blockIdx.y * 32;
  int tx = threadIdx.x & 31, ty = threadIdx.x >> 5;
  const u16* src = QKV + (size_t)b * SS * NQKV + 2048 + h * DHH;
  for (int i = ty; i < 32; i += 8)
    t[i][tx] = src[(size_t)(s0 + i) * NQKV + d0 + tx];
  __syncthreads();
  u16* dst = VT + (size_t)bh * DHH * SS;
  for (int i = ty; i < 32; i += 8)
    dst[(size_t)(d0 + i) * SS + s0 + tx] = t[tx][i];
}

// ---------------- MFMA GEMM, BK=32, 4 LDS buffers, 3-deep prefetch, counted vmcnt (T4) ----------------
// Per step t: issue loads for tile t+3 -> compute buf[t&3] -> vmcnt(2*CPW) (tile t+1 landed;
// loads for t+2,t+3 stay in flight ACROSS the barrier) -> s_barrier. Never drains to 0 in
// steady state: the waited loads were issued 3 steps (~900cyc) ago -> near-zero stall.
// Write-after-read safe: step t writes buf[(t+3)&3]=buf[(t-1)&3], whose reads finished
// before the end-of-(t-1) barrier. Operand-swapped MFMA epilogue: packed stores.
template<int TM, int TN>
__global__ __launch_bounds__(256) void gemm_db(
    const u16* __restrict__ A, const u16* __restrict__ Bt,
    const float* __restrict__ bias, const float* __restrict__ res,
    void* __restrict__ Cv, int M, int N, int K, int relu, int writeBf16)
{
  constexpr int ACH = TM / 16;
  constexpr int BCH = TN / 16;
  constexpr int CH1 = ACH + BCH;
  constexpr int CPW = CH1 / 4;          // loads per thread per K-step (BK=32)
  constexpr int MI  = TM / 32;
  constexpr int NI  = TN / 32;
  static_assert(CPW == 3 || CPW == 4, "vmcnt immediates assume CPW in {3,4}");

  __shared__ __align__(16) u16 As[4][TM * 32];   // [buf][TM rows x 32 cols]
  __shared__ __align__(16) u16 Bs[4][TN * 32];

  int tid  = threadIdx.x;
  int wave = tid >> 6, lane = tid & 63;
  int quad = lane >> 4, l16 = lane & 15;

  int gx = gridDim.x, gy = gridDim.y;
  int bid = blockIdx.x + gx * blockIdx.y;
  int xcd = bid & 7, idx = bid >> 3;
  int by  = xcd * (gy >> 3) + idx / gx;
  int bx  = idx % gx;

  int m0 = by * TM, n0 = bx * TN;
  int wm = (wave >> 1) * (TM / 2), wn = (wave & 1) * (TN / 2);

  floatx4 acc[MI][NI] = {};

  int srow = lane >> 2;
  int scol = (lane & 3) * 8;
  const u16* gptr[CPW]; u16* lp0[CPW]; int bstep[CPW];
#pragma unroll
  for (int k = 0; k < CPW; k++){
    int c = wave * CPW + k;
    if (c < ACH){
      gptr[k]  = A + (size_t)(m0 + c*16 + srow) * K + scol;
      lp0[k]   = &As[0][c * 512];
      bstep[k] = TM * 32;
    } else {
      int cb = c - ACH;
      gptr[k]  = Bt + (size_t)(n0 + cb*16 + srow) * K + scol;
      lp0[k]   = &Bs[0][cb * 512];
      bstep[k] = TN * 32;
    }
  }

  int nsteps = K >> 5;    // BK=32; K>=1024 -> nsteps>=32

  // prologue: issue tiles 0,1,2 (3-deep), wait tile 0, barrier
#pragma unroll
  for (int pt = 0; pt < 3; pt++){
#pragma unroll
    for (int k = 0; k < CPW; k++){
      gl2lds16(gptr[k], lp0[k] + pt * bstep[k]);
      gptr[k] += 32;
    }
  }
  if constexpr (CPW == 4) VMW(8); else VMW(6);
  __builtin_amdgcn_sched_barrier(0);
  __builtin_amdgcn_s_barrier();
  __builtin_amdgcn_sched_barrier(0);

  for (int t = 0; t < nsteps; ++t){
    if (t + 3 < nsteps){
      int bi = (t + 3) & 3;
#pragma unroll
      for (int k = 0; k < CPW; k++){
        gl2lds16(gptr[k], lp0[k] + bi * bstep[k]);
        gptr[k] += 32;
      }
    }
    int cur = t & 3;
    __builtin_amdgcn_s_setprio(1);
    short8 af[MI], bf[NI];
#pragma unroll
    for (int i = 0; i < MI; i++)
      af[i] = *(short8*)&As[cur][(wm + i*16 + l16)*32 + quad*8];
#pragma unroll
    for (int j = 0; j < NI; j++)
      bf[j] = *(short8*)&Bs[cur][(wn + j*16 + l16)*32 + quad*8];
#pragma unroll
    for (int i = 0; i < MI; i++)
#pragma unroll
      for (int j = 0; j < NI; j++)
        acc[i][j] = __builtin_amdgcn_mfma_f32_16x16x32_bf16(bf[j], af[i], acc[i][j], 0,0,0);
    __builtin_amdgcn_s_setprio(0);

    if (t + 1 < nsteps){
      if (t < nsteps - 3){        // steady: wait tile t+1 only (2*CPW stay in flight)
        if constexpr (CPW == 4) VMW(8); else VMW(6);
      } else if (t == nsteps - 3){
        if constexpr (CPW == 4) VMW(4); else VMW(3);
      } else {                    // t == nsteps-2: last prefetch outstanding
        VMW(0);
      }
      __builtin_amdgcn_sched_barrier(0);
      __builtin_amdgcn_s_barrier();
      __builtin_amdgcn_sched_barrier(0);
    }
  }

  // Swapped-D epilogue: C[m0+wm+i*16+l16][n0+wn+j*16+quad*4 + 0..3] = acc[i][j][0..3]
  u16*   Cb = (u16*)Cv;
  float* Cf = (float*)Cv;
#pragma unroll
  for (int i = 0; i < MI; i++){
    int row = m0 + wm + i*16 + l16;
#pragma unroll
    for (int j = 0; j < NI; j++){
      int col = n0 + wn + j*16 + quad*4;
      float v0 = acc[i][j][0], v1 = acc[i][j][1], v2 = acc[i][j][2], v3 = acc[i][j][3];
      if (bias){
        const float4 bb = *(const float4*)&bias[col];
        v0 += bb.x; v1 += bb.y; v2 += bb.z; v3 += bb.w;
      }
      if (relu){
        v0 = v0 > 0.f ? v0 : 0.f; v1 = v1 > 0.f ? v1 : 0.f;
        v2 = v2 > 0.f ? v2 : 0.f; v3 = v3 > 0.f ? v3 : 0.f;
      }
      if (res){
        const float4 rr = *(const float4*)&res[(size_t)row * N + col];
        v0 += rr.x; v1 += rr.y; v2 += rr.z; v3 += rr.w;
      }
      if (writeBf16){
        ushort4_t o = { f2b(v0), f2b(v1), f2b(v2), f2b(v3) };
        *(ushort4_t*)&Cb[(size_t)row * N + col] = o;
      } else {
        float4 o; o.x = v0; o.y = v1; o.z = v2; o.w = v3;
        *(float4*)&Cf[(size_t)row * N + col] = o;
      }
    }
  }
}

// ---------------- causal flash attention, 512 threads / 8 waves, Q-tile=128 ----------------
// Paired q-tiles share Ks/VTs (64KB swizzled LDS); T12 swapped-QK softmax:
// sacc = mfma(K, Q) puts one q-row x 4 consecutive k-cols per lane -> P-store is
// 2x v_cvt_pk_bf16_f32 + 1 ds_write_b64 per st; l-reduction = 1 scalar + 2 shuffles.
#define KT 128

__global__ __launch_bounds__(512) void attn_k(
    const u16* __restrict__ QKV, const u16* __restrict__ VT, u16* __restrict__ O)
{
  int bh = blockIdx.x;                       // 0..31
  int b = bh >> 4, h = bh & 15;
  int t  = (int)gridDim.y - 1 - blockIdx.y;  // 0..15, LPT: heaviest first
  const u16* Qb_  = QKV + (size_t)b * SS * NQKV + h * DHH;
  const u16* Kb_  = Qb_ + 1024;
  const u16* VTb_ = VT + (size_t)bh * DHH * SS;

  __shared__ __align__(16) u16 Ks [KT * 64];      // [s][dh], swizzled
  __shared__ __align__(16) u16 VTs[DHH * 128];    // [dh][s], swizzled
  __shared__ __align__(16) u16 Ps [8][16 * 128];  // per-wave [q][s], swizzled

  int tid = threadIdx.x;
  int wave = tid >> 6, lane = tid & 63;
  int g = wave >> 2, w = wave & 3;
  int quad = lane >> 4, l16 = lane & 15;
  int qrow = t * 128 + g * 64 + w * 16;

  short8 qf0, qf1;
  {
    const u16* qp = Qb_ + (size_t)(qrow + l16) * NQKV + quad*8;
    qf0 = *(const short8*)qp;
    qf1 = *(const short8*)(qp + 32);
  }

  float lsum = 0.f;
  floatx4 oacc[4] = {};

  int nk = t + 1;
  int lim = w + 4 * g;                       // diagonal-tile live st bound
  int qcol = qrow + l16;                     // this lane's q row (swapped-QK: l16 = q)
  const float qs = 0.125f * 1.44269504088896f;   // scale * log2(e)

  // T14 prologue: issue tile-0 K/V loads into registers (2 iters x 512 threads)
  short8 kreg[2], vreg[2];
#pragma unroll
  for (int it = 0; it < 2; it++){
    int gg = tid + it * 512;
    kreg[it] = *(const short8*)(Kb_ + (size_t)(gg >> 3) * NQKV + (gg & 7) * 8);
    vreg[it] = *(const short8*)(VTb_ + (size_t)(gg >> 4) * SS + (gg & 15) * 8);
  }

  for (int kt = 0; kt < nk; kt++){
    int k0 = kt * KT;
    __syncthreads();                 // all waves done reading prev LDS tile
#pragma unroll
    for (int it = 0; it < 2; it++){
      int gg = tid + it * 512;
      { int row = gg >> 3, idx = (row * 64 + (gg & 7) * 8) ^ ((row & 7) << 3);
        *(short8*)&Ks[idx] = kreg[it]; }
      { int row = gg >> 4, idx = (row * 128 + (gg & 15) * 8) ^ ((row & 7) << 3);
        *(short8*)&VTs[idx] = vreg[it]; }
    }
    __syncthreads();                 // tile ready for all waves

    // T14: prefetch next tile AFTER barrier; latency hides under compute below.
    if (kt + 1 < nk){
      int kn = k0 + KT;
#pragma unroll
      for (int it = 0; it < 2; it++){
        int gg = tid + it * 512;
        kreg[it] = *(const short8*)(Kb_ + (size_t)(kn + (gg >> 3)) * NQKV + (gg & 7) * 8);
        vreg[it] = *(const short8*)(VTb_ + (size_t)(gg >> 4) * SS + kn + (gg & 15) * 8);
      }
    }

    bool last = (kt == nk - 1);
    int stmax = last ? lim : 7;
    floatx4 sacc[8] = {};
    __builtin_amdgcn_s_setprio(1);
#pragma unroll
    for (int st = 0; st < 8; st++){
      if (st <= stmax){
        int r0i = (st*16 + l16) * 64;
        int sw  = (l16 & 7) << 3;
        short8 kb0 = *(short8*)&Ks[(r0i + quad*8) ^ sw];
        short8 kb1 = *(short8*)&Ks[(r0i + 32 + quad*8) ^ sw];
        // swapped operands: D col(l16)=q-row, rows(quad*4+r)=k-cols
        sacc[st] = __builtin_amdgcn_mfma_f32_16x16x32_bf16(kb0, qf0, sacc[st], 0,0,0);
        sacc[st] = __builtin_amdgcn_mfma_f32_16x16x32_bf16(kb1, qf1, sacc[st], 0,0,0);
      }
    }
    __builtin_amdgcn_s_setprio(0);

    // softmax: lane owns q-row (l16), k-cols k0+st*16+quad*4+(0..3) -> packed b64 stores
#pragma unroll
    for (int st = 0; st < 8; st++){
      int base = (l16 * 128 + st*16 + quad*4) ^ ((l16 & 7) << 3);
      if (st <= stmax){
        float e0 = exp2f(sacc[st][0] * qs);
        float e1 = exp2f(sacc[st][1] * qs);
        float e2 = exp2f(sacc[st][2] * qs);
        float e3 = exp2f(sacc[st][3] * qs);
        if (last){
          int colb = k0 + st*16 + quad*4;
          e0 = (colb + 0 <= qcol) ? e0 : 0.f;
          e1 = (colb + 1 <= qcol) ? e1 : 0.f;
          e2 = (colb + 2 <= qcol) ? e2 : 0.f;
          e3 = (colb + 3 <= qcol) ? e3 : 0.f;
        }
        lsum += (e0 + e1) + (e2 + e3);
        unsigned int lo, hi;
        asm("v_cvt_pk_bf16_f32 %0, %1, %2" : "=v"(lo) : "v"(e0), "v"(e1));
        asm("v_cvt_pk_bf16_f32 %0, %1, %2" : "=v"(hi) : "v"(e2), "v"(e3));
        uint2 pk; pk.x = lo; pk.y = hi;
        *(uint2*)&Ps[wave][base] = pk;
      } else {
        uint2 z; z.x = 0u; z.y = 0u;
        *(uint2*)&Ps[wave][base] = z;
      }
    }
    asm volatile("s_waitcnt lgkmcnt(0)" ::: "memory");   // per-wave Ps write->read

    int cmax = last ? (lim >> 1) : 3;
    short8 pa[4];
#pragma unroll
    for (int c = 0; c < 4; c++)
      pa[c] = *(short8*)&Ps[wave][(l16 * 128 + c*32 + quad*8) ^ ((l16 & 7) << 3)];
    __builtin_amdgcn_s_setprio(1);
#pragma unroll
    for (int ost = 0; ost < 4; ost++){
#pragma unroll
      for (int c = 0; c < 4; c++){
        if (c <= cmax){
          short8 vb = *(short8*)&VTs[((ost*16 + l16) * 128 + c*32 + quad*8) ^ ((l16 & 7) << 3)];
          oacc[ost] = __builtin_amdgcn_mfma_f32_16x16x32_bf16(pa[c], vb, oacc[ost], 0,0,0);
        }
      }
    }
    __builtin_amdgcn_s_setprio(0);
  }

  // reduce lsum over quads (lane's partial covers its 4 k-cols x all st)
  lsum += __shfl_xor(lsum, 16, 64);
  lsum += __shfl_xor(lsum, 32, 64);
  float linv = 1.0f / lsum;          // row (lane&15) inverse, uniform across quads
  float inv[4];
#pragma unroll
  for (int r = 0; r < 4; r++)
    inv[r] = __shfl(linv, quad*4 + r, 64);   // row quad*4+r inverse (matches oacc rows)

#pragma unroll
  for (int ost = 0; ost < 4; ost++)
#pragma unroll
    for (int r = 0; r < 4; r++){
      int s  = qrow + quad*4 + r;
      int dh = ost*16 + l16;
      O[((size_t)b * SS + s) * DDIM + h * DHH + dh] = f2b(oacc[ost][r] * inv[r]);
    }
}

// ---------------- launch ----------------
extern "C" void kernel_launch(void* const* d_in, const int* in_sizes, int n_in,
                              void* d_out, int out_size, void* d_ws, size_t ws_size,
                              hipStream_t stream) {
  const float* X   = (const float*)d_in[0];
  const float* g1  = (const float*)d_in[2];
  const float* be1 = (const float*)d_in[3];
  const float* Wq  = (const float*)d_in[4];
  const float* bq  = (const float*)d_in[5];
  const float* Wk  = (const float*)d_in[6];
  const float* bk  = (const float*)d_in[7];
  const float* Wv  = (const float*)d_in[8];
  const float* bv  = (const float*)d_in[9];
  const float* W0  = (const float*)d_in[10];
  const float* b0  = (const float*)d_in[11];
  const float* g2  = (const float*)d_in[12];
  const float* be2 = (const float*)d_in[13];
  const float* W1  = (const float*)d_in[14];
  const float* b1  = (const float*)d_in[15];
  const float* W2  = (const float*)d_in[16];
  const float* b2  = (const float*)d_in[17];
  float* out = (float*)d_out;   // holds X1 (f32) after W0, final output after FFN2

  u16* ws16 = (u16*)d_ws;
  u16* wqkvT = ws16;                         // 3,145,728  [3072][1024]
  u16* w0T   = ws16 + 3145728;               // 1,048,576  [1024][1024]
  u16* w2T   = ws16;                         // aliases region0 (dead after QKV+W0 gemms)
  u16* w1T   = ws16 + 4194304;               // 4,194,304  [4096][1024]
  u16* QKVb  = ws16 + 8388608;               // 12,582,912 [4096][3072]
  u16* VTb   = ws16 + 8388608 + 12582912;    // 4,194,304  [32][64][2048]
  u16* hb    = ws16 + 8388608;               // aliases QKV+VT [4096][4096]
  u16* Xn    = ws16 + 25165824;              // 4,194,304 (Xn -> attnB -> Xn2)
  u16* attnB = Xn;
  float* biasQKV = (float*)(ws16 + 29360128);  // 3072 f32

  // fused LN1 + weight prep (1 launch)
  prep_ln1_k<<<dim3(12300), 256, 0, stream>>>(X, g1, be1, Xn,
      Wq, Wk, Wv, W0, W1, bq, bk, bv, wqkvT, w0T, w1T, biasQKV);

  // fused QKV projection: 128x128, 4-buf counted-vmcnt pipeline, 768 blocks
  gemm_db<128,128><<<dim3(24, 32), 256, 0, stream>>>(Xn, wqkvT, biasQKV, nullptr, QKVb,
      BS, NQKV, 1024, 0, 1);

  vt_k<<<dim3(64, 2, 32), 256, 0, stream>>>(QKVb, VTb);

  // attention: 512 threads / 8 waves, Q-tile 128, swapped-QK packed softmax
  attn_k<<<dim3(32, 16), 512, 0, stream>>>(QKVb, VTb, attnB);

  // W0 projection + residual(X) -> X1 f32 in d_out. 64x128, 48KB
  gemm_db<64,128><<<dim3(8, 64), 256, 0, stream>>>(attnB, w0T, b0, X, out,
      BS, DDIM, 1024, 0, 0);

  // fused LN2 + W2 transpose (region0 dead now)
  w2t_ln2_k<<<dim3(8192), 256, 0, stream>>>(out, g2, be2, Xn, W2, w2T);

  // FFN1: 128x128, 1024 blocks
  gemm_db<128,128><<<dim3(32, 32), 256, 0, stream>>>(Xn, w1T, b1, nullptr, hb,
      BS, DFF_, 1024, 1, 1);
  // FFN2: 64x128, in-place residual accumulate into d_out (X1)
  gemm_db<64,128><<<dim3(8, 64), 256, 0, stream>>>(hb, w2T, b2, out, out,
      BS, DDIM, DFF_, 0, 0);
}

// Round 13
// 366.927 us; speedup vs baseline: 1.0805x; 1.0805x over previous
//
#include <hip/hip_runtime.h>
#include <hip/hip_bf16.h>

#define BB 2
#define SS 2048
#define DDIM 1024
#define HH 16
#define DHH 64
#define DFF_ 4096
#define BS 4096   // B*S
#define NQKV 3072 // Q|K|V concatenated feature dim

typedef unsigned short u16;
using short8  = __attribute__((ext_vector_type(8))) short;
using floatx4 = __attribute__((ext_vector_type(4))) float;
using ushort4_t = __attribute__((ext_vector_type(4))) unsigned short;

__device__ __forceinline__ u16 f2b(float f){
  union { unsigned int u; float f; } v; v.f = f;
  unsigned int u = v.u;
  u += 0x7FFFu + ((u >> 16) & 1u);   // RNE
  return (u16)(u >> 16);
}

__device__ __forceinline__ void gl2lds16(const u16* g, u16* l){
  __builtin_amdgcn_global_load_lds((const __attribute__((address_space(1))) void*)g,
                                   (__attribute__((address_space(3))) void*)l, 16, 0, 0);
}

// ---------------- LayerNorm row (device): y_bf16 = (x-mu)*rsqrt(var+eps)*gamma + beta ----------------
__device__ __forceinline__ void ln_row(const float* __restrict__ x,
                                       const float* __restrict__ gamma,
                                       const float* __restrict__ beta,
                                       u16* __restrict__ y, int row, float* smem){
  const float4* xr = (const float4*)(x + (size_t)row * DDIM);
  int tid = threadIdx.x;
  float4 v = xr[tid];
  float s  = v.x + v.y + v.z + v.w;
  float ss = v.x*v.x + v.y*v.y + v.z*v.z + v.w*v.w;
  for (int o = 1; o < 64; o <<= 1){ s += __shfl_xor(s, o, 64); ss += __shfl_xor(ss, o, 64); }
  int wid = tid >> 6;
  if ((tid & 63) == 0){ smem[wid] = s; smem[wid + 4] = ss; }
  __syncthreads();
  s  = smem[0] + smem[1] + smem[2] + smem[3];
  ss = smem[4] + smem[5] + smem[6] + smem[7];
  float mu  = s / (float)DDIM;
  float var = ss / (float)DDIM - mu * mu;
  float rs  = rsqrtf(var + 1e-5f);
  const float4* gp = (const float4*)gamma;
  const float4* bp = (const float4*)beta;
  float4 g = gp[tid], b = bp[tid];
  u16* yr = y + (size_t)row * DDIM + tid*4;
  yr[0] = f2b((v.x - mu) * rs * g.x + b.x);
  yr[1] = f2b((v.y - mu) * rs * g.y + b.y);
  yr[2] = f2b((v.z - mu) * rs * g.z + b.z);
  yr[3] = f2b((v.w - mu) * rs * g.w + b.w);
}

// ---------------- transpose+cast tile helper: out_bf16[c][r] = in_f32[r][c] ----------------
__device__ __forceinline__ void tcast(const float* __restrict__ in, u16* __restrict__ out,
                                      int R, int C, int tile, float (*sh)[33]){
  int nr = R >> 5;
  int tr = tile % nr, tc = tile / nr;
  int r0 = tr * 32, c0 = tc * 32;
  int tx = threadIdx.x & 31, ty = threadIdx.x >> 5;   // ty 0..7
  for (int i = ty; i < 32; i += 8)
    sh[i][tx] = in[(size_t)(r0 + i) * C + c0 + tx];
  __syncthreads();
  for (int i = ty; i < 32; i += 8)
    out[(size_t)(c0 + i) * R + r0 + tx] = f2b(sh[tx][i]);
}

// ---------------- fused: LN1 + Wq/Wk/Wv/W0/W1 transposes + bias concat, 1 launch ----------------
__global__ __launch_bounds__(256) void prep_ln1_k(
    const float* __restrict__ X, const float* __restrict__ g1, const float* __restrict__ be1,
    u16* __restrict__ Xn,
    const float* __restrict__ Wq, const float* __restrict__ Wk, const float* __restrict__ Wv,
    const float* __restrict__ W0, const float* __restrict__ W1,
    const float* __restrict__ bq, const float* __restrict__ bk, const float* __restrict__ bv,
    u16* __restrict__ wqkvT, u16* __restrict__ w0T, u16* __restrict__ w1T,
    float* __restrict__ biasQKV)
{
  __shared__ float sh[32][33];
  __shared__ float smem8[8];
  int id = blockIdx.x;
  if (id < 4096){
    ln_row(X, g1, be1, Xn, id, smem8);
  } else if (id < 7168){
    int lid2 = id - 4096;
    int which = lid2 >> 10, lid = lid2 & 1023;
    const float* src = which == 0 ? Wq : (which == 1 ? Wk : Wv);
    u16* dst = wqkvT + (size_t)which * 1048576;
    int bat = lid >> 6, t = lid & 63;              // 64 tiles per [1024][64] head
    tcast(src + (size_t)bat * 65536, dst + (size_t)bat * 65536, 1024, 64, t, sh);
  } else if (id < 8192){
    tcast(W0, w0T, 1024, 1024, id - 7168, sh);
  } else if (id < 12288){
    tcast(W1, w1T, 1024, 4096, id - 8192, sh);
  } else {
    int idx = (id - 12288) * 256 + threadIdx.x;
    if (idx < 3072){
      float v = idx < 1024 ? bq[idx] : (idx < 2048 ? bk[idx - 1024] : bv[idx - 2048]);
      biasQKV[idx] = v;
    }
  }
}

// ---------------- fused: LN2 + W2 transpose, 1 launch ----------------
__global__ __launch_bounds__(256) void w2t_ln2_k(
    const float* __restrict__ X1, const float* __restrict__ g2, const float* __restrict__ be2,
    u16* __restrict__ Xn2, const float* __restrict__ W2, u16* __restrict__ w2T)
{
  __shared__ float sh[32][33];
  __shared__ float smem8[8];
  int id = blockIdx.x;
  if (id < 4096){
    ln_row(X1, g2, be2, Xn2, id, smem8);
  } else {
    int tile = id - 4096;
    int tr = tile / 32, tc = tile % 32;   // R=4096, C=1024
    int r0 = tr * 32, c0 = tc * 32;
    int tx = threadIdx.x & 31, ty = threadIdx.x >> 5;
    for (int i = ty; i < 32; i += 8)
      sh[i][tx] = W2[(size_t)(r0 + i) * 1024 + c0 + tx];
    __syncthreads();
    for (int i = ty; i < 32; i += 8)
      w2T[(size_t)(c0 + i) * 4096 + r0 + tx] = f2b(sh[tx][i]);
  }
}

// ---------------- V-transpose: VT[bh][dh][s] = QKV[b*S+s][2048 + h*64 + dh] ----------------
__global__ __launch_bounds__(256) void vt_k(const u16* __restrict__ QKV, u16* __restrict__ VT){
  __shared__ u16 t[32][33];
  int bh = blockIdx.z; int b = bh >> 4, h = bh & 15;
  int s0 = blockIdx.x * 32, d0 = blockIdx.y * 32;
  int tx = threadIdx.x & 31, ty = threadIdx.x >> 5;
  const u16* src = QKV + (size_t)b * SS * NQKV + 2048 + h * DHH;
  for (int i = ty; i < 32; i += 8)
    t[i][tx] = src[(size_t)(s0 + i) * NQKV + d0 + tx];
  __syncthreads();
  u16* dst = VT + (size_t)bh * DHH * SS;
  for (int i = ty; i < 32; i += 8)
    dst[(size_t)(d0 + i) * SS + s0 + tx] = t[tx][i];
}

// ---------------- MFMA GEMM, BK=64 (2 planes), DOUBLE-BUFFERED (T3-minimum schedule) ----------------
// Per iter: issue next tile's global_load_lds -> compute current buffer -> vmcnt(0)+barrier.
// Load latency hides under the MFMA phase (verified recipe, learn_hip m248v2).
// Operand-swapped MFMA epilogue: packed ushort4/float4 stores.
template<int TM, int TN>
__global__ __launch_bounds__(256) void gemm_db(
    const u16* __restrict__ A, const u16* __restrict__ Bt,
    const float* __restrict__ bias, const float* __restrict__ res,
    void* __restrict__ Cv, int M, int N, int K, int relu, int writeBf16)
{
  constexpr int ACH = TM / 16;
  constexpr int BCH = TN / 16;
  constexpr int CH1 = ACH + BCH;
  constexpr int CPW = (2 * CH1) / 4;
  constexpr int MI  = TM / 32;
  constexpr int NI  = TN / 32;

  __shared__ __align__(16) u16 As[2][2][TM * 32];   // [buf][plane][...]
  __shared__ __align__(16) u16 Bs[2][2][TN * 32];

  int tid  = threadIdx.x;
  int wave = tid >> 6, lane = tid & 63;
  int quad = lane >> 4, l16 = lane & 15;

  int gx = gridDim.x, gy = gridDim.y;
  int bid = blockIdx.x + gx * blockIdx.y;
  int xcd = bid & 7, idx = bid >> 3;
  int by  = xcd * (gy >> 3) + idx / gx;
  int bx  = idx % gx;

  int m0 = by * TM, n0 = bx * TN;
  int wm = (wave >> 1) * (TM / 2), wn = (wave & 1) * (TN / 2);

  floatx4 acc[MI][NI] = {};

  int srow = lane >> 2;
  int scol = (lane & 3) * 8;
  const u16* gptr[CPW]; u16* lp0[CPW]; int lstep[CPW];
#pragma unroll
  for (int k = 0; k < CPW; k++){
    int c = wave * CPW + k;
    int p = c / CH1, cc = c % CH1;
    if (cc < ACH){
      gptr[k]  = A + (size_t)(m0 + cc*16 + srow) * K + p*32 + scol;
      lp0[k]   = &As[0][p][cc * 512];
      lstep[k] = 2 * TM * 32;           // u16 elems from buf0 to buf1
    } else {
      gptr[k]  = Bt + (size_t)(n0 + (cc-ACH)*16 + srow) * K + p*32 + scol;
      lp0[k]   = &Bs[0][p][(cc-ACH) * 512];
      lstep[k] = 2 * TN * 32;
    }
  }

  int nsteps = K >> 6;

  // prologue: stage tile 0 into buf0, drain, barrier
#pragma unroll
  for (int k = 0; k < CPW; k++){ gl2lds16(gptr[k], lp0[k]); gptr[k] += 64; }
  asm volatile("s_waitcnt vmcnt(0)" ::: "memory");
  __builtin_amdgcn_sched_barrier(0);
  __builtin_amdgcn_s_barrier();
  __builtin_amdgcn_sched_barrier(0);

  for (int t = 0; t < nsteps; ++t){
    int cur = t & 1;
    if (t + 1 < nsteps){
#pragma unroll
      for (int k = 0; k < CPW; k++){
        gl2lds16(gptr[k], lp0[k] + (cur ? 0 : lstep[k]));
        gptr[k] += 64;
      }
    }
    __builtin_amdgcn_s_setprio(1);
#pragma unroll
    for (int p = 0; p < 2; p++){
      short8 af[MI], bf[NI];
#pragma unroll
      for (int i = 0; i < MI; i++)
        af[i] = *(short8*)&As[cur][p][(wm + i*16 + l16)*32 + quad*8];
#pragma unroll
      for (int j = 0; j < NI; j++)
        bf[j] = *(short8*)&Bs[cur][p][(wn + j*16 + l16)*32 + quad*8];
#pragma unroll
      for (int i = 0; i < MI; i++)
#pragma unroll
        for (int j = 0; j < NI; j++)
          acc[i][j] = __builtin_amdgcn_mfma_f32_16x16x32_bf16(bf[j], af[i], acc[i][j], 0,0,0);
    }
    __builtin_amdgcn_s_setprio(0);
    if (t + 1 < nsteps){
      asm volatile("s_waitcnt vmcnt(0)" ::: "memory");   // next tile landed (own wave)
      __builtin_amdgcn_sched_barrier(0);
      __builtin_amdgcn_s_barrier();                      // all waves: landed + reads done
      __builtin_amdgcn_sched_barrier(0);
    }
  }

  // Swapped-D epilogue: C[m0+wm+i*16+l16][n0+wn+j*16+quad*4 + 0..3] = acc[i][j][0..3]
  u16*   Cb = (u16*)Cv;
  float* Cf = (float*)Cv;
#pragma unroll
  for (int i = 0; i < MI; i++){
    int row = m0 + wm + i*16 + l16;
#pragma unroll
    for (int j = 0; j < NI; j++){
      int col = n0 + wn + j*16 + quad*4;
      float v0 = acc[i][j][0], v1 = acc[i][j][1], v2 = acc[i][j][2], v3 = acc[i][j][3];
      if (bias){
        const float4 bb = *(const float4*)&bias[col];
        v0 += bb.x; v1 += bb.y; v2 += bb.z; v3 += bb.w;
      }
      if (relu){
        v0 = v0 > 0.f ? v0 : 0.f; v1 = v1 > 0.f ? v1 : 0.f;
        v2 = v2 > 0.f ? v2 : 0.f; v3 = v3 > 0.f ? v3 : 0.f;
      }
      if (res){
        const float4 rr = *(const float4*)&res[(size_t)row * N + col];
        v0 += rr.x; v1 += rr.y; v2 += rr.z; v3 += rr.w;
      }
      if (writeBf16){
        ushort4_t o = { f2b(v0), f2b(v1), f2b(v2), f2b(v3) };
        *(ushort4_t*)&Cb[(size_t)row * N + col] = o;
      } else {
        float4 o; o.x = v0; o.y = v1; o.z = v2; o.w = v3;
        *(float4*)&Cf[(size_t)row * N + col] = o;
      }
    }
  }
}

// ---------------- causal flash attention, 512 threads / 8 waves, Q-tile=128 ----------------
// Paired q-tiles share Ks/VTs (64KB swizzled LDS); T12 swapped-QK softmax:
// sacc = mfma(K, Q) puts one q-row x 4 consecutive k-cols per lane -> P-store is
// 2x v_cvt_pk_bf16_f32 + 1 ds_write_b64 per st; l-reduction = 1 scalar + 2 shuffles.
#define KT 128

__global__ __launch_bounds__(512) void attn_k(
    const u16* __restrict__ QKV, const u16* __restrict__ VT, u16* __restrict__ O)
{
  int bh = blockIdx.x;                       // 0..31
  int b = bh >> 4, h = bh & 15;
  int t  = (int)gridDim.y - 1 - blockIdx.y;  // 0..15, LPT: heaviest first
  const u16* Qb_  = QKV + (size_t)b * SS * NQKV + h * DHH;
  const u16* Kb_  = Qb_ + 1024;
  const u16* VTb_ = VT + (size_t)bh * DHH * SS;

  __shared__ __align__(16) u16 Ks [KT * 64];      // [s][dh], swizzled
  __shared__ __align__(16) u16 VTs[DHH * 128];    // [dh][s], swizzled
  __shared__ __align__(16) u16 Ps [8][16 * 128];  // per-wave [q][s], swizzled

  int tid = threadIdx.x;
  int wave = tid >> 6, lane = tid & 63;
  int g = wave >> 2, w = wave & 3;
  int quad = lane >> 4, l16 = lane & 15;
  int qrow = t * 128 + g * 64 + w * 16;

  short8 qf0, qf1;
  {
    const u16* qp = Qb_ + (size_t)(qrow + l16) * NQKV + quad*8;
    qf0 = *(const short8*)qp;
    qf1 = *(const short8*)(qp + 32);
  }

  float lsum = 0.f;
  floatx4 oacc[4] = {};

  int nk = t + 1;
  int lim = w + 4 * g;                       // diagonal-tile live st bound
  int qcol = qrow + l16;                     // this lane's q row (swapped-QK: l16 = q)
  const float qs = 0.125f * 1.44269504088896f;   // scale * log2(e)

  // T14 prologue: issue tile-0 K/V loads into registers (2 iters x 512 threads)
  short8 kreg[2], vreg[2];
#pragma unroll
  for (int it = 0; it < 2; it++){
    int gg = tid + it * 512;
    kreg[it] = *(const short8*)(Kb_ + (size_t)(gg >> 3) * NQKV + (gg & 7) * 8);
    vreg[it] = *(const short8*)(VTb_ + (size_t)(gg >> 4) * SS + (gg & 15) * 8);
  }

  for (int kt = 0; kt < nk; kt++){
    int k0 = kt * KT;
    __syncthreads();                 // all waves done reading prev LDS tile
#pragma unroll
    for (int it = 0; it < 2; it++){
      int gg = tid + it * 512;
      { int row = gg >> 3, idx = (row * 64 + (gg & 7) * 8) ^ ((row & 7) << 3);
        *(short8*)&Ks[idx] = kreg[it]; }
      { int row = gg >> 4, idx = (row * 128 + (gg & 15) * 8) ^ ((row & 7) << 3);
        *(short8*)&VTs[idx] = vreg[it]; }
    }
    __syncthreads();                 // tile ready for all waves

    // T14: prefetch next tile AFTER barrier; latency hides under compute below.
    if (kt + 1 < nk){
      int kn = k0 + KT;
#pragma unroll
      for (int it = 0; it < 2; it++){
        int gg = tid + it * 512;
        kreg[it] = *(const short8*)(Kb_ + (size_t)(kn + (gg >> 3)) * NQKV + (gg & 7) * 8);
        vreg[it] = *(const short8*)(VTb_ + (size_t)(gg >> 4) * SS + kn + (gg & 15) * 8);
      }
    }

    bool last = (kt == nk - 1);
    int stmax = last ? lim : 7;
    floatx4 sacc[8] = {};
    __builtin_amdgcn_s_setprio(1);
#pragma unroll
    for (int st = 0; st < 8; st++){
      if (st <= stmax){
        int r0i = (st*16 + l16) * 64;
        int sw  = (l16 & 7) << 3;
        short8 kb0 = *(short8*)&Ks[(r0i + quad*8) ^ sw];
        short8 kb1 = *(short8*)&Ks[(r0i + 32 + quad*8) ^ sw];
        // swapped operands: D col(l16)=q-row, rows(quad*4+r)=k-cols
        sacc[st] = __builtin_amdgcn_mfma_f32_16x16x32_bf16(kb0, qf0, sacc[st], 0,0,0);
        sacc[st] = __builtin_amdgcn_mfma_f32_16x16x32_bf16(kb1, qf1, sacc[st], 0,0,0);
      }
    }
    __builtin_amdgcn_s_setprio(0);

    // softmax: lane owns q-row (l16), k-cols k0+st*16+quad*4+(0..3) -> packed b64 stores
#pragma unroll
    for (int st = 0; st < 8; st++){
      int base = (l16 * 128 + st*16 + quad*4) ^ ((l16 & 7) << 3);
      if (st <= stmax){
        float e0 = exp2f(sacc[st][0] * qs);
        float e1 = exp2f(sacc[st][1] * qs);
        float e2 = exp2f(sacc[st][2] * qs);
        float e3 = exp2f(sacc[st][3] * qs);
        if (last){
          int colb = k0 + st*16 + quad*4;
          e0 = (colb + 0 <= qcol) ? e0 : 0.f;
          e1 = (colb + 1 <= qcol) ? e1 : 0.f;
          e2 = (colb + 2 <= qcol) ? e2 : 0.f;
          e3 = (colb + 3 <= qcol) ? e3 : 0.f;
        }
        lsum += (e0 + e1) + (e2 + e3);
        unsigned int lo, hi;
        asm("v_cvt_pk_bf16_f32 %0, %1, %2" : "=v"(lo) : "v"(e0), "v"(e1));
        asm("v_cvt_pk_bf16_f32 %0, %1, %2" : "=v"(hi) : "v"(e2), "v"(e3));
        uint2 pk; pk.x = lo; pk.y = hi;
        *(uint2*)&Ps[wave][base] = pk;
      } else {
        uint2 z; z.x = 0u; z.y = 0u;
        *(uint2*)&Ps[wave][base] = z;
      }
    }
    asm volatile("s_waitcnt lgkmcnt(0)" ::: "memory");   // per-wave Ps write->read

    int cmax = last ? (lim >> 1) : 3;
    short8 pa[4];
#pragma unroll
    for (int c = 0; c < 4; c++)
      pa[c] = *(short8*)&Ps[wave][(l16 * 128 + c*32 + quad*8) ^ ((l16 & 7) << 3)];
    __builtin_amdgcn_s_setprio(1);
#pragma unroll
    for (int ost = 0; ost < 4; ost++){
#pragma unroll
      for (int c = 0; c < 4; c++){
        if (c <= cmax){
          short8 vb = *(short8*)&VTs[((ost*16 + l16) * 128 + c*32 + quad*8) ^ ((l16 & 7) << 3)];
          oacc[ost] = __builtin_amdgcn_mfma_f32_16x16x32_bf16(pa[c], vb, oacc[ost], 0,0,0);
        }
      }
    }
    __builtin_amdgcn_s_setprio(0);
  }

  // reduce lsum over quads (lane's partial covers its 4 k-cols x all st)
  lsum += __shfl_xor(lsum, 16, 64);
  lsum += __shfl_xor(lsum, 32, 64);
  float linv = 1.0f / lsum;          // row (lane&15) inverse, uniform across quads
  float inv[4];
#pragma unroll
  for (int r = 0; r < 4; r++)
    inv[r] = __shfl(linv, quad*4 + r, 64);   // row quad*4+r inverse (matches oacc rows)

#pragma unroll
  for (int ost = 0; ost < 4; ost++)
#pragma unroll
    for (int r = 0; r < 4; r++){
      int s  = qrow + quad*4 + r;
      int dh = ost*16 + l16;
      O[((size_t)b * SS + s) * DDIM + h * DHH + dh] = f2b(oacc[ost][r] * inv[r]);
    }
}

// ---------------- launch ----------------
extern "C" void kernel_launch(void* const* d_in, const int* in_sizes, int n_in,
                              void* d_out, int out_size, void* d_ws, size_t ws_size,
                              hipStream_t stream) {
  const float* X   = (const float*)d_in[0];
  const float* g1  = (const float*)d_in[2];
  const float* be1 = (const float*)d_in[3];
  const float* Wq  = (const float*)d_in[4];
  const float* bq  = (const float*)d_in[5];
  const float* Wk  = (const float*)d_in[6];
  const float* bk  = (const float*)d_in[7];
  const float* Wv  = (const float*)d_in[8];
  const float* bv  = (const float*)d_in[9];
  const float* W0  = (const float*)d_in[10];
  const float* b0  = (const float*)d_in[11];
  const float* g2  = (const float*)d_in[12];
  const float* be2 = (const float*)d_in[13];
  const float* W1  = (const float*)d_in[14];
  const float* b1  = (const float*)d_in[15];
  const float* W2  = (const float*)d_in[16];
  const float* b2  = (const float*)d_in[17];
  float* out = (float*)d_out;   // holds X1 (f32) after W0, final output after FFN2

  u16* ws16 = (u16*)d_ws;
  u16* wqkvT = ws16;                         // 3,145,728  [3072][1024]
  u16* w0T   = ws16 + 3145728;               // 1,048,576  [1024][1024]
  u16* w2T   = ws16;                         // aliases region0 (dead after QKV+W0 gemms)
  u16* w1T   = ws16 + 4194304;               // 4,194,304  [4096][1024]
  u16* QKVb  = ws16 + 8388608;               // 12,582,912 [4096][3072]
  u16* VTb   = ws16 + 8388608 + 12582912;    // 4,194,304  [32][64][2048]
  u16* hb    = ws16 + 8388608;               // aliases QKV+VT [4096][4096]
  u16* Xn    = ws16 + 25165824;              // 4,194,304 (Xn -> attnB -> Xn2)
  u16* attnB = Xn;
  float* biasQKV = (float*)(ws16 + 29360128);  // 3072 f32

  // fused LN1 + weight prep (1 launch)
  prep_ln1_k<<<dim3(12300), 256, 0, stream>>>(X, g1, be1, Xn,
      Wq, Wk, Wv, W0, W1, bq, bk, bv, wqkvT, w0T, w1T, biasQKV);

  // fused QKV projection: 128x128 dbuf, 768 blocks
  gemm_db<128,128><<<dim3(24, 32), 256, 0, stream>>>(Xn, wqkvT, biasQKV, nullptr, QKVb,
      BS, NQKV, 1024, 0, 1);

  vt_k<<<dim3(64, 2, 32), 256, 0, stream>>>(QKVb, VTb);

  // attention: 512 threads / 8 waves, Q-tile 128, swapped-QK packed softmax
  attn_k<<<dim3(32, 16), 512, 0, stream>>>(QKVb, VTb, attnB);

  // W0 projection + residual(X) -> X1 f32 in d_out. 64x128 dbuf (48KB, 3/CU)
  gemm_db<64,128><<<dim3(8, 64), 256, 0, stream>>>(attnB, w0T, b0, X, out,
      BS, DDIM, 1024, 0, 0);

  // fused LN2 + W2 transpose (region0 dead now)
  w2t_ln2_k<<<dim3(8192), 256, 0, stream>>>(out, g2, be2, Xn, W2, w2T);

  // FFN1: 128x128 dbuf, 1024 blocks
  gemm_db<128,128><<<dim3(32, 32), 256, 0, stream>>>(Xn, w1T, b1, nullptr, hb,
      BS, DFF_, 1024, 1, 1);
  // FFN2: 64x128 dbuf, in-place residual accumulate into d_out (X1)
  gemm_db<64,128><<<dim3(8, 64), 256, 0, stream>>>(hb, w2T, b2, out, out,
      BS, DDIM, DFF_, 0, 0);
}

// Round 14
// 357.002 us; speedup vs baseline: 1.1105x; 1.0278x over previous
//
#include <hip/hip_runtime.h>
#include <hip/hip_bf16.h>

#define BB 2
#define SS 2048
#define DDIM 1024
#define HH 16
#define DHH 64
#define DFF_ 4096
#define BS 4096   // B*S
#define NQKV 3072 // Q|K|V concatenated feature dim

typedef unsigned short u16;
using short8  = __attribute__((ext_vector_type(8))) short;
using floatx4 = __attribute__((ext_vector_type(4))) float;
using ushort4_t = __attribute__((ext_vector_type(4))) unsigned short;

__device__ __forceinline__ u16 f2b(float f){
  union { unsigned int u; float f; } v; v.f = f;
  unsigned int u = v.u;
  u += 0x7FFFu + ((u >> 16) & 1u);   // RNE
  return (u16)(u >> 16);
}

__device__ __forceinline__ void gl2lds16(const u16* g, u16* l){
  __builtin_amdgcn_global_load_lds((const __attribute__((address_space(1))) void*)g,
                                   (__attribute__((address_space(3))) void*)l, 16, 0, 0);
}

// ---------------- LayerNorm row (device): y_bf16 = (x-mu)*rsqrt(var+eps)*gamma + beta ----------------
__device__ __forceinline__ void ln_row(const float* __restrict__ x,
                                       const float* __restrict__ gamma,
                                       const float* __restrict__ beta,
                                       u16* __restrict__ y, int row, float* smem){
  const float4* xr = (const float4*)(x + (size_t)row * DDIM);
  int tid = threadIdx.x;
  float4 v = xr[tid];
  float s  = v.x + v.y + v.z + v.w;
  float ss = v.x*v.x + v.y*v.y + v.z*v.z + v.w*v.w;
  for (int o = 1; o < 64; o <<= 1){ s += __shfl_xor(s, o, 64); ss += __shfl_xor(ss, o, 64); }
  int wid = tid >> 6;
  if ((tid & 63) == 0){ smem[wid] = s; smem[wid + 4] = ss; }
  __syncthreads();
  s  = smem[0] + smem[1] + smem[2] + smem[3];
  ss = smem[4] + smem[5] + smem[6] + smem[7];
  float mu  = s / (float)DDIM;
  float var = ss / (float)DDIM - mu * mu;
  float rs  = rsqrtf(var + 1e-5f);
  const float4* gp = (const float4*)gamma;
  const float4* bp = (const float4*)beta;
  float4 g = gp[tid], b = bp[tid];
  u16* yr = y + (size_t)row * DDIM + tid*4;
  yr[0] = f2b((v.x - mu) * rs * g.x + b.x);
  yr[1] = f2b((v.y - mu) * rs * g.y + b.y);
  yr[2] = f2b((v.z - mu) * rs * g.z + b.z);
  yr[3] = f2b((v.w - mu) * rs * g.w + b.w);
}

// ---------------- transpose+cast tile helper: out_bf16[c][r] = in_f32[r][c] ----------------
__device__ __forceinline__ void tcast(const float* __restrict__ in, u16* __restrict__ out,
                                      int R, int C, int tile, float (*sh)[33]){
  int nr = R >> 5;
  int tr = tile % nr, tc = tile / nr;
  int r0 = tr * 32, c0 = tc * 32;
  int tx = threadIdx.x & 31, ty = threadIdx.x >> 5;   // ty 0..7
  for (int i = ty; i < 32; i += 8)
    sh[i][tx] = in[(size_t)(r0 + i) * C + c0 + tx];
  __syncthreads();
  for (int i = ty; i < 32; i += 8)
    out[(size_t)(c0 + i) * R + r0 + tx] = f2b(sh[tx][i]);
}

// ---------------- fused: LN1 + Wq/Wk/Wv/W0/W1 transposes + bias concat, 1 launch ----------------
__global__ __launch_bounds__(256) void prep_ln1_k(
    const float* __restrict__ X, const float* __restrict__ g1, const float* __restrict__ be1,
    u16* __restrict__ Xn,
    const float* __restrict__ Wq, const float* __restrict__ Wk, const float* __restrict__ Wv,
    const float* __restrict__ W0, const float* __restrict__ W1,
    const float* __restrict__ bq, const float* __restrict__ bk, const float* __restrict__ bv,
    u16* __restrict__ wqkvT, u16* __restrict__ w0T, u16* __restrict__ w1T,
    float* __restrict__ biasQKV)
{
  __shared__ float sh[32][33];
  __shared__ float smem8[8];
  int id = blockIdx.x;
  if (id < 4096){
    ln_row(X, g1, be1, Xn, id, smem8);
  } else if (id < 7168){
    int lid2 = id - 4096;
    int which = lid2 >> 10, lid = lid2 & 1023;
    const float* src = which == 0 ? Wq : (which == 1 ? Wk : Wv);
    u16* dst = wqkvT + (size_t)which * 1048576;
    int bat = lid >> 6, t = lid & 63;              // 64 tiles per [1024][64] head
    tcast(src + (size_t)bat * 65536, dst + (size_t)bat * 65536, 1024, 64, t, sh);
  } else if (id < 8192){
    tcast(W0, w0T, 1024, 1024, id - 7168, sh);
  } else if (id < 12288){
    tcast(W1, w1T, 1024, 4096, id - 8192, sh);
  } else {
    int idx = (id - 12288) * 256 + threadIdx.x;
    if (idx < 3072){
      float v = idx < 1024 ? bq[idx] : (idx < 2048 ? bk[idx - 1024] : bv[idx - 2048]);
      biasQKV[idx] = v;
    }
  }
}

// ---------------- fused: LN2 + W2 transpose, 1 launch ----------------
__global__ __launch_bounds__(256) void w2t_ln2_k(
    const float* __restrict__ X1, const float* __restrict__ g2, const float* __restrict__ be2,
    u16* __restrict__ Xn2, const float* __restrict__ W2, u16* __restrict__ w2T)
{
  __shared__ float sh[32][33];
  __shared__ float smem8[8];
  int id = blockIdx.x;
  if (id < 4096){
    ln_row(X1, g2, be2, Xn2, id, smem8);
  } else {
    int tile = id - 4096;
    int tr = tile / 32, tc = tile % 32;   // R=4096, C=1024
    int r0 = tr * 32, c0 = tc * 32;
    int tx = threadIdx.x & 31, ty = threadIdx.x >> 5;
    for (int i = ty; i < 32; i += 8)
      sh[i][tx] = W2[(size_t)(r0 + i) * 1024 + c0 + tx];
    __syncthreads();
    for (int i = ty; i < 32; i += 8)
      w2T[(size_t)(c0 + i) * 4096 + r0 + tx] = f2b(sh[tx][i]);
  }
}

// ---------------- V-transpose: VT[bh][dh][s] = QKV[b*S+s][2048 + h*64 + dh] ----------------
__global__ __launch_bounds__(256) void vt_k(const u16* __restrict__ QKV, u16* __restrict__ VT){
  __shared__ u16 t[32][33];
  int bh = blockIdx.z; int b = bh >> 4, h = bh & 15;
  int s0 = blockIdx.x * 32, d0 = blockIdx.y * 32;
  int tx = threadIdx.x & 31, ty = threadIdx.x >> 5;
  const u16* src = QKV + (size_t)b * SS * NQKV + 2048 + h * DHH;
  for (int i = ty; i < 32; i += 8)
    t[i][tx] = src[(size_t)(s0 + i) * NQKV + d0 + tx];
  __syncthreads();
  u16* dst = VT + (size_t)bh * DHH * SS;
  for (int i = ty; i < 32; i += 8)
    dst[(size_t)(d0 + i) * SS + s0 + tx] = t[tx][i];
}

// ---------------- MFMA GEMM, BK=64 (2 planes), DOUBLE-BUFFERED + T2 fragment swizzle ----------------
// Per iter: issue next tile's global_load_lds -> compute current buffer -> vmcnt(0)+barrier.
// T2 (rule #21, both-sides): LDS dest stays LINEAR (gl2lds constraint); the per-lane GLOBAL
// source col is pre-swizzled (scol ^= ((lane>>3)&3)<<3) and the fragment ds_read applies the
// same XOR (quad*8 ^ ((l16>>1)&3)<<3). Rows 0-7 then cover all 8 distinct 16B slots ->
// 8-way bank conflict becomes 2-way (free, m136). Coalescing unchanged (per-row permutation).
// Operand-swapped MFMA epilogue: packed ushort4/float4 stores.
template<int TM, int TN>
__global__ __launch_bounds__(256) void gemm_db(
    const u16* __restrict__ A, const u16* __restrict__ Bt,
    const float* __restrict__ bias, const float* __restrict__ res,
    void* __restrict__ Cv, int M, int N, int K, int relu, int writeBf16)
{
  constexpr int ACH = TM / 16;
  constexpr int BCH = TN / 16;
  constexpr int CH1 = ACH + BCH;
  constexpr int CPW = (2 * CH1) / 4;
  constexpr int MI  = TM / 32;
  constexpr int NI  = TN / 32;

  __shared__ __align__(16) u16 As[2][2][TM * 32];   // [buf][plane][...]
  __shared__ __align__(16) u16 Bs[2][2][TN * 32];

  int tid  = threadIdx.x;
  int wave = tid >> 6, lane = tid & 63;
  int quad = lane >> 4, l16 = lane & 15;

  int gx = gridDim.x, gy = gridDim.y;
  int bid = blockIdx.x + gx * blockIdx.y;
  int xcd = bid & 7, idx = bid >> 3;
  int by  = xcd * (gy >> 3) + idx / gx;
  int bx  = idx % gx;

  int m0 = by * TM, n0 = bx * TN;
  int wm = (wave >> 1) * (TM / 2), wn = (wave & 1) * (TN / 2);

  floatx4 acc[MI][NI] = {};

  int srow = lane >> 2;
  int scol = ((lane & 3) * 8) ^ (((lane >> 3) & 3) << 3);   // T2 pre-swizzled source col
  const u16* gptr[CPW]; u16* lp0[CPW]; int lstep[CPW];
#pragma unroll
  for (int k = 0; k < CPW; k++){
    int c = wave * CPW + k;
    int p = c / CH1, cc = c % CH1;
    if (cc < ACH){
      gptr[k]  = A + (size_t)(m0 + cc*16 + srow) * K + p*32 + scol;
      lp0[k]   = &As[0][p][cc * 512];
      lstep[k] = 2 * TM * 32;           // u16 elems from buf0 to buf1
    } else {
      gptr[k]  = Bt + (size_t)(n0 + (cc-ACH)*16 + srow) * K + p*32 + scol;
      lp0[k]   = &Bs[0][p][(cc-ACH) * 512];
      lstep[k] = 2 * TN * 32;
    }
  }

  int nsteps = K >> 6;
  int rsw = ((l16 >> 1) & 3) << 3;      // T2 read-side XOR (same involution)

  // prologue: stage tile 0 into buf0, drain, barrier
#pragma unroll
  for (int k = 0; k < CPW; k++){ gl2lds16(gptr[k], lp0[k]); gptr[k] += 64; }
  asm volatile("s_waitcnt vmcnt(0)" ::: "memory");
  __builtin_amdgcn_sched_barrier(0);
  __builtin_amdgcn_s_barrier();
  __builtin_amdgcn_sched_barrier(0);

  for (int t = 0; t < nsteps; ++t){
    int cur = t & 1;
    if (t + 1 < nsteps){
#pragma unroll
      for (int k = 0; k < CPW; k++){
        gl2lds16(gptr[k], lp0[k] + (cur ? 0 : lstep[k]));
        gptr[k] += 64;
      }
    }
    __builtin_amdgcn_s_setprio(1);
#pragma unroll
    for (int p = 0; p < 2; p++){
      short8 af[MI], bf[NI];
#pragma unroll
      for (int i = 0; i < MI; i++)
        af[i] = *(short8*)&As[cur][p][(wm + i*16 + l16)*32 + ((quad*8) ^ rsw)];
#pragma unroll
      for (int j = 0; j < NI; j++)
        bf[j] = *(short8*)&Bs[cur][p][(wn + j*16 + l16)*32 + ((quad*8) ^ rsw)];
#pragma unroll
      for (int i = 0; i < MI; i++)
#pragma unroll
        for (int j = 0; j < NI; j++)
          acc[i][j] = __builtin_amdgcn_mfma_f32_16x16x32_bf16(bf[j], af[i], acc[i][j], 0,0,0);
    }
    __builtin_amdgcn_s_setprio(0);
    if (t + 1 < nsteps){
      asm volatile("s_waitcnt vmcnt(0)" ::: "memory");   // next tile landed (own wave)
      __builtin_amdgcn_sched_barrier(0);
      __builtin_amdgcn_s_barrier();                      // all waves: landed + reads done
      __builtin_amdgcn_sched_barrier(0);
    }
  }

  // Swapped-D epilogue: C[m0+wm+i*16+l16][n0+wn+j*16+quad*4 + 0..3] = acc[i][j][0..3]
  u16*   Cb = (u16*)Cv;
  float* Cf = (float*)Cv;
#pragma unroll
  for (int i = 0; i < MI; i++){
    int row = m0 + wm + i*16 + l16;
#pragma unroll
    for (int j = 0; j < NI; j++){
      int col = n0 + wn + j*16 + quad*4;
      float v0 = acc[i][j][0], v1 = acc[i][j][1], v2 = acc[i][j][2], v3 = acc[i][j][3];
      if (bias){
        const float4 bb = *(const float4*)&bias[col];
        v0 += bb.x; v1 += bb.y; v2 += bb.z; v3 += bb.w;
      }
      if (relu){
        v0 = v0 > 0.f ? v0 : 0.f; v1 = v1 > 0.f ? v1 : 0.f;
        v2 = v2 > 0.f ? v2 : 0.f; v3 = v3 > 0.f ? v3 : 0.f;
      }
      if (res){
        const float4 rr = *(const float4*)&res[(size_t)row * N + col];
        v0 += rr.x; v1 += rr.y; v2 += rr.z; v3 += rr.w;
      }
      if (writeBf16){
        ushort4_t o = { f2b(v0), f2b(v1), f2b(v2), f2b(v3) };
        *(ushort4_t*)&Cb[(size_t)row * N + col] = o;
      } else {
        float4 o; o.x = v0; o.y = v1; o.z = v2; o.w = v3;
        *(float4*)&Cf[(size_t)row * N + col] = o;
      }
    }
  }
}

// ---------------- causal flash attention, 512 threads / 8 waves, Q-tile=128 ----------------
// Paired q-tiles share Ks/VTs (64KB swizzled LDS); T12 swapped-QK softmax:
// sacc = mfma(K, Q) puts one q-row x 4 consecutive k-cols per lane -> P-store is
// 2x v_cvt_pk_bf16_f32 + 1 ds_write_b64 per st; l-reduction = 1 scalar + 2 shuffles.
#define KT 128

__global__ __launch_bounds__(512) void attn_k(
    const u16* __restrict__ QKV, const u16* __restrict__ VT, u16* __restrict__ O)
{
  int bh = blockIdx.x;                       // 0..31
  int b = bh >> 4, h = bh & 15;
  int t  = (int)gridDim.y - 1 - blockIdx.y;  // 0..15, LPT: heaviest first
  const u16* Qb_  = QKV + (size_t)b * SS * NQKV + h * DHH;
  const u16* Kb_  = Qb_ + 1024;
  const u16* VTb_ = VT + (size_t)bh * DHH * SS;

  __shared__ __align__(16) u16 Ks [KT * 64];      // [s][dh], swizzled
  __shared__ __align__(16) u16 VTs[DHH * 128];    // [dh][s], swizzled
  __shared__ __align__(16) u16 Ps [8][16 * 128];  // per-wave [q][s], swizzled

  int tid = threadIdx.x;
  int wave = tid >> 6, lane = tid & 63;
  int g = wave >> 2, w = wave & 3;
  int quad = lane >> 4, l16 = lane & 15;
  int qrow = t * 128 + g * 64 + w * 16;

  short8 qf0, qf1;
  {
    const u16* qp = Qb_ + (size_t)(qrow + l16) * NQKV + quad*8;
    qf0 = *(const short8*)qp;
    qf1 = *(const short8*)(qp + 32);
  }

  float lsum = 0.f;
  floatx4 oacc[4] = {};

  int nk = t + 1;
  int lim = w + 4 * g;                       // diagonal-tile live st bound
  int qcol = qrow + l16;                     // this lane's q row (swapped-QK: l16 = q)
  const float qs = 0.125f * 1.44269504088896f;   // scale * log2(e)

  // T14 prologue: issue tile-0 K/V loads into registers (2 iters x 512 threads)
  short8 kreg[2], vreg[2];
#pragma unroll
  for (int it = 0; it < 2; it++){
    int gg = tid + it * 512;
    kreg[it] = *(const short8*)(Kb_ + (size_t)(gg >> 3) * NQKV + (gg & 7) * 8);
    vreg[it] = *(const short8*)(VTb_ + (size_t)(gg >> 4) * SS + (gg & 15) * 8);
  }

  for (int kt = 0; kt < nk; kt++){
    int k0 = kt * KT;
    __syncthreads();                 // all waves done reading prev LDS tile
#pragma unroll
    for (int it = 0; it < 2; it++){
      int gg = tid + it * 512;
      { int row = gg >> 3, idx = (row * 64 + (gg & 7) * 8) ^ ((row & 7) << 3);
        *(short8*)&Ks[idx] = kreg[it]; }
      { int row = gg >> 4, idx = (row * 128 + (gg & 15) * 8) ^ ((row & 7) << 3);
        *(short8*)&VTs[idx] = vreg[it]; }
    }
    __syncthreads();                 // tile ready for all waves

    // T14: prefetch next tile AFTER barrier; latency hides under compute below.
    if (kt + 1 < nk){
      int kn = k0 + KT;
#pragma unroll
      for (int it = 0; it < 2; it++){
        int gg = tid + it * 512;
        kreg[it] = *(const short8*)(Kb_ + (size_t)(kn + (gg >> 3)) * NQKV + (gg & 7) * 8);
        vreg[it] = *(const short8*)(VTb_ + (size_t)(gg >> 4) * SS + kn + (gg & 15) * 8);
      }
    }

    bool last = (kt == nk - 1);
    int stmax = last ? lim : 7;
    floatx4 sacc[8] = {};
    __builtin_amdgcn_s_setprio(1);
#pragma unroll
    for (int st = 0; st < 8; st++){
      if (st <= stmax){
        int r0i = (st*16 + l16) * 64;
        int sw  = (l16 & 7) << 3;
        short8 kb0 = *(short8*)&Ks[(r0i + quad*8) ^ sw];
        short8 kb1 = *(short8*)&Ks[(r0i + 32 + quad*8) ^ sw];
        // swapped operands: D col(l16)=q-row, rows(quad*4+r)=k-cols
        sacc[st] = __builtin_amdgcn_mfma_f32_16x16x32_bf16(kb0, qf0, sacc[st], 0,0,0);
        sacc[st] = __builtin_amdgcn_mfma_f32_16x16x32_bf16(kb1, qf1, sacc[st], 0,0,0);
      }
    }
    __builtin_amdgcn_s_setprio(0);

    // softmax: lane owns q-row (l16), k-cols k0+st*16+quad*4+(0..3) -> packed b64 stores
#pragma unroll
    for (int st = 0; st < 8; st++){
      int base = (l16 * 128 + st*16 + quad*4) ^ ((l16 & 7) << 3);
      if (st <= stmax){
        float e0 = exp2f(sacc[st][0] * qs);
        float e1 = exp2f(sacc[st][1] * qs);
        float e2 = exp2f(sacc[st][2] * qs);
        float e3 = exp2f(sacc[st][3] * qs);
        if (last){
          int colb = k0 + st*16 + quad*4;
          e0 = (colb + 0 <= qcol) ? e0 : 0.f;
          e1 = (colb + 1 <= qcol) ? e1 : 0.f;
          e2 = (colb + 2 <= qcol) ? e2 : 0.f;
          e3 = (colb + 3 <= qcol) ? e3 : 0.f;
        }
        lsum += (e0 + e1) + (e2 + e3);
        unsigned int lo, hi;
        asm("v_cvt_pk_bf16_f32 %0, %1, %2" : "=v"(lo) : "v"(e0), "v"(e1));
        asm("v_cvt_pk_bf16_f32 %0, %1, %2" : "=v"(hi) : "v"(e2), "v"(e3));
        uint2 pk; pk.x = lo; pk.y = hi;
        *(uint2*)&Ps[wave][base] = pk;
      } else {
        uint2 z; z.x = 0u; z.y = 0u;
        *(uint2*)&Ps[wave][base] = z;
      }
    }
    asm volatile("s_waitcnt lgkmcnt(0)" ::: "memory");   // per-wave Ps write->read

    int cmax = last ? (lim >> 1) : 3;
    short8 pa[4];
#pragma unroll
    for (int c = 0; c < 4; c++)
      pa[c] = *(short8*)&Ps[wave][(l16 * 128 + c*32 + quad*8) ^ ((l16 & 7) << 3)];
    __builtin_amdgcn_s_setprio(1);
#pragma unroll
    for (int ost = 0; ost < 4; ost++){
#pragma unroll
      for (int c = 0; c < 4; c++){
        if (c <= cmax){
          short8 vb = *(short8*)&VTs[((ost*16 + l16) * 128 + c*32 + quad*8) ^ ((l16 & 7) << 3)];
          oacc[ost] = __builtin_amdgcn_mfma_f32_16x16x32_bf16(pa[c], vb, oacc[ost], 0,0,0);
        }
      }
    }
    __builtin_amdgcn_s_setprio(0);
  }

  // reduce lsum over quads (lane's partial covers its 4 k-cols x all st)
  lsum += __shfl_xor(lsum, 16, 64);
  lsum += __shfl_xor(lsum, 32, 64);
  float linv = 1.0f / lsum;          // row (lane&15) inverse, uniform across quads
  float inv[4];
#pragma unroll
  for (int r = 0; r < 4; r++)
    inv[r] = __shfl(linv, quad*4 + r, 64);   // row quad*4+r inverse (matches oacc rows)

#pragma unroll
  for (int ost = 0; ost < 4; ost++)
#pragma unroll
    for (int r = 0; r < 4; r++){
      int s  = qrow + quad*4 + r;
      int dh = ost*16 + l16;
      O[((size_t)b * SS + s) * DDIM + h * DHH + dh] = f2b(oacc[ost][r] * inv[r]);
    }
}

// ---------------- launch ----------------
extern "C" void kernel_launch(void* const* d_in, const int* in_sizes, int n_in,
                              void* d_out, int out_size, void* d_ws, size_t ws_size,
                              hipStream_t stream) {
  const float* X   = (const float*)d_in[0];
  const float* g1  = (const float*)d_in[2];
  const float* be1 = (const float*)d_in[3];
  const float* Wq  = (const float*)d_in[4];
  const float* bq  = (const float*)d_in[5];
  const float* Wk  = (const float*)d_in[6];
  const float* bk  = (const float*)d_in[7];
  const float* Wv  = (const float*)d_in[8];
  const float* bv  = (const float*)d_in[9];
  const float* W0  = (const float*)d_in[10];
  const float* b0  = (const float*)d_in[11];
  const float* g2  = (const float*)d_in[12];
  const float* be2 = (const float*)d_in[13];
  const float* W1  = (const float*)d_in[14];
  const float* b1  = (const float*)d_in[15];
  const float* W2  = (const float*)d_in[16];
  const float* b2  = (const float*)d_in[17];
  float* out = (float*)d_out;   // holds X1 (f32) after W0, final output after FFN2

  u16* ws16 = (u16*)d_ws;
  u16* wqkvT = ws16;                         // 3,145,728  [3072][1024]
  u16* w0T   = ws16 + 3145728;               // 1,048,576  [1024][1024]
  u16* w2T   = ws16;                         // aliases region0 (dead after QKV+W0 gemms)
  u16* w1T   = ws16 + 4194304;               // 4,194,304  [4096][1024]
  u16* QKVb  = ws16 + 8388608;               // 12,582,912 [4096][3072]
  u16* VTb   = ws16 + 8388608 + 12582912;    // 4,194,304  [32][64][2048]
  u16* hb    = ws16 + 8388608;               // aliases QKV+VT [4096][4096]
  u16* Xn    = ws16 + 25165824;              // 4,194,304 (Xn -> attnB -> Xn2)
  u16* attnB = Xn;
  float* biasQKV = (float*)(ws16 + 29360128);  // 3072 f32

  // fused LN1 + weight prep (1 launch)
  prep_ln1_k<<<dim3(12300), 256, 0, stream>>>(X, g1, be1, Xn,
      Wq, Wk, Wv, W0, W1, bq, bk, bv, wqkvT, w0T, w1T, biasQKV);

  // fused QKV projection: 128x128 dbuf + T2 swizzle, 768 blocks
  gemm_db<128,128><<<dim3(24, 32), 256, 0, stream>>>(Xn, wqkvT, biasQKV, nullptr, QKVb,
      BS, NQKV, 1024, 0, 1);

  vt_k<<<dim3(64, 2, 32), 256, 0, stream>>>(QKVb, VTb);

  // attention: 512 threads / 8 waves, Q-tile 128, swapped-QK packed softmax
  attn_k<<<dim3(32, 16), 512, 0, stream>>>(QKVb, VTb, attnB);

  // W0 projection + residual(X) -> X1 f32 in d_out. 64x128 dbuf (48KB, 3/CU)
  gemm_db<64,128><<<dim3(8, 64), 256, 0, stream>>>(attnB, w0T, b0, X, out,
      BS, DDIM, 1024, 0, 0);

  // fused LN2 + W2 transpose (region0 dead now)
  w2t_ln2_k<<<dim3(8192), 256, 0, stream>>>(out, g2, be2, Xn, W2, w2T);

  // FFN1: 128x128 dbuf + T2 swizzle, 1024 blocks
  gemm_db<128,128><<<dim3(32, 32), 256, 0, stream>>>(Xn, w1T, b1, nullptr, hb,
      BS, DFF_, 1024, 1, 1);
  // FFN2: 64x128 dbuf, in-place residual accumulate into d_out (X1)
  gemm_db<64,128><<<dim3(8, 64), 256, 0, stream>>>(hb, w2T, b2, out, out,
      BS, DDIM, DFF_, 0, 0);
}